// Round 4
// baseline (239.293 us; speedup 1.0000x reference)
//
#include <hip/hip_runtime.h>
#include <hip/hip_bf16.h>
#include <math.h>

#define NPIX 4096      // 64*64
#define MAXB 32
#define MAXL 64
#define ROIH 8
#define NB   4
#define NC   128
#define ROI_N 8388608  // 4*32*8*64*128 elements per roi tensor

// ---------------------------------------------------------------------------
// Kernel 1: per-batch score/box reconstruct + serial NMS (one block per batch)
// ---------------------------------------------------------------------------
__global__ __launch_bounds__(256) void nms_kernel(const float* __restrict__ bbox,
                                                  float* __restrict__ out_nms)
{
    const int b = blockIdx.x;
    const int t = threadIdx.x;

    __shared__ float s_score[NPIX];        // 16 KB
    __shared__ float s_box[NPIX][4];       // 64 KB
    __shared__ float s_area[NPIX];         // 16 KB
    __shared__ float s_rv[4];
    __shared__ int   s_ri[4];

    const float* src = bbox + (size_t)b * NPIX * 5;

    // stage scores / boxes / areas into LDS
    for (int i = 0; i < 16; ++i) {
        int p = i * 256 + t;
        int y = p >> 6, x = p & 63;
        float c0 = src[p * 5 + 0];
        float c1 = src[p * 5 + 1];
        float c2 = src[p * 5 + 2];
        float c3 = src[p * 5 + 3];
        float c4 = src[p * 5 + 4];
        float sc = 1.0f / (1.0f + expf(-c0));
        float x1 = 8.0f * ((float)x - c1);
        float y1 = 8.0f * ((float)y - c2);
        float x2 = 8.0f * ((float)x + c3);
        float y2 = 8.0f * ((float)y + c4);
        s_score[p]  = sc;
        s_box[p][0] = x1; s_box[p][1] = y1; s_box[p][2] = x2; s_box[p][3] = y2;
        s_area[p]   = (x2 - x1) * (y2 - y1);
    }
    __syncthreads();

    unsigned valid = 0xFFFFu;   // bit i <-> pixel p = i*256 + t

    for (int it = 0; it < MAXB; ++it) {
        // ---- masked argmax (first-index tie-break, like jnp.argmax) ----
        float best = -INFINITY;
        int   bidx = 0x7FFFFFFF;
        for (int i = 0; i < 16; ++i) {
            if (valid & (1u << i)) {
                int p = i * 256 + t;            // ascending p
                float v = s_score[p];
                if (v > best) { best = v; bidx = p; }   // strict > keeps lowest p
            }
        }
        // wave (64-lane) butterfly reduce
        for (int off = 32; off; off >>= 1) {
            float ov = __shfl_xor(best, off);
            int   oi = __shfl_xor(bidx, off);
            if (ov > best || (ov == best && oi < bidx)) { best = ov; bidx = oi; }
        }
        int wave = t >> 6;
        if ((t & 63) == 0) { s_rv[wave] = best; s_ri[wave] = bidx; }
        __syncthreads();
        best = s_rv[0]; bidx = s_ri[0];
        #pragma unroll
        for (int wv = 1; wv < 4; ++wv) {
            float ov = s_rv[wv]; int oi = s_ri[wv];
            if (ov > best || (ov == best && oi < bidx)) { best = ov; bidx = oi; }
        }
        __syncthreads();   // all reads of s_rv/s_ri done before next-iter writes

        bool ok = (best > -INFINITY);   // any valid candidate left
        int  j  = bidx;
        float bx1 = 0.f, by1 = 0.f, bx2 = 0.f, by2 = 0.f, barea = 0.f;
        if (ok) {
            bx1 = s_box[j][0]; by1 = s_box[j][1];
            bx2 = s_box[j][2]; by2 = s_box[j][3];
            barea = s_area[j];
        }

        // ---- emit nms box (keep = ok && score >= SCORE_THR) ----
        if (t == 0) {
            bool keep = ok && (best >= 0.3f);
            float* o = out_nms + ((size_t)b * MAXB + it) * 4;
            o[0] = keep ? bx1 : 0.f;
            o[1] = keep ? by1 : 0.f;
            o[2] = keep ? bx2 : 0.f;
            o[3] = keep ? by2 : 0.f;
        }

        // ---- suppress by IoU against selected box ----
        if (ok) {
            for (int i = 0; i < 16; ++i) {
                if (valid & (1u << i)) {
                    int p = i * 256 + t;
                    float x1 = s_box[p][0], y1 = s_box[p][1];
                    float x2 = s_box[p][2], y2 = s_box[p][3];
                    float iw = fmaxf(fminf(x2, bx2) - fmaxf(x1, bx1), 0.f);
                    float ih = fmaxf(fminf(y2, by2) - fmaxf(y1, by1), 0.f);
                    float inter = iw * ih;
                    float iou = inter / (s_area[p] + barea - inter + 1e-9f);
                    if (iou > 0.5f) valid &= ~(1u << i);
                }
            }
        }
    }
}

// ---------------------------------------------------------------------------
// Kernel 2: dual-direction ROI pooling, one thread per output element.
// FP contraction OFF: coordinate math must round exactly like the numpy ref
// (separately-rounded mul/add; true divisions), else floor() can flip.
// ---------------------------------------------------------------------------
#pragma clang fp contract(off)

__global__ __launch_bounds__(256) void roi_kernel(const float* __restrict__ fmap,
                                                  const float* __restrict__ nms,
                                                  float* __restrict__ out_h,
                                                  float* __restrict__ out_w,
                                                  float* __restrict__ out_v,
                                                  float* __restrict__ out_hh)
{
    int idx = blockIdx.x * 256 + threadIdx.x;       // [0, 2*ROI_N)
    int dir = (idx >= ROI_N) ? 1 : 0;               // 0 = horizontal, 1 = vertical
    int el  = idx - dir * ROI_N;                    // [0, ROI_N)
    int tb  = el >> 16;                             // box index b*32+box, [0,128)
    int within = el & 65535;                        // 512 pos x 128 ch
    int pos = within >> 7;                          // [0,512)
    int ch  = within & 127;

    const float* nb = nms + tb * 4;
    float x1 = nb[0] * 0.125f, y1 = nb[1] * 0.125f;  // /8 exact (pow2)
    float x2 = nb[2] * 0.125f, y2 = nb[3] * 0.125f;
    float w = x2 - x1, h = y2 - y1;
    bool is_dir = (dir == 0) ? (w >= h) : (w < h);
    if (!is_dir) { x1 = 0.f; y1 = 0.f; x2 = 0.f; y2 = 0.f; }
    w = x2 - x1; h = y2 - y1;

    bool  non_zero = (w >= 0.1f) || (h >= 0.1f);
    float bw = (w <= 0.f) ? 1e-4f : w;
    float bh = (h <= 0.f) ? 1e-4f : h;
    float ratio = non_zero ? ((dir == 0) ? __fdiv_rn(bw, bh) : __fdiv_rn(bh, bw)) : 0.f;
    int   n = (int)fminf(ceilf(ratio * 8.0f), 64.0f);   // *8 exact (pow2)
    float length_f = fmaxf((float)n, 2.0f);
    float fmask = non_zero ? 1.f : 0.f;

    float map_w, map_h, mask;
    int rr, cc;
    if (dir == 0) {
        map_w = __fdiv_rn(bw, length_f - 1.0f);
        map_h = __fdiv_rn(bh, 7.0f);                 // TRUE division, like ref
        rr = pos >> 6; cc = pos & 63;                // (8, 64): rr=y, cc=x
        mask = (cc < n) ? fmask : 0.f;
    } else {
        map_w = __fdiv_rn(bw, 7.0f);                 // TRUE division, like ref
        map_h = __fdiv_rn(bh, length_f - 1.0f);
        rr = pos >> 3; cc = pos & 7;                 // (64, 8): rr=y, cc=x
        mask = (rr < n) ? fmask : 0.f;
    }

    // separately-rounded mul then add (no FMA) — must match numpy exactly,
    // since floor() below is discontinuous.
    float x = __fadd_rn(__fmul_rn((float)cc, map_w), x1);
    float y = __fadd_rn(__fmul_rn((float)rr, map_h), y1);

    // bilinear, exact replication of the reference formula (incl. the
    // reference's swapped Ib/Ic weight pairing and clipped-index weights)
    float x0f = floorf(x), y0f = floorf(y);
    int ix0 = min(max((int)x0f,     0), 63);
    int ix1 = min(max((int)x0f + 1, 0), 63);
    int iy0 = min(max((int)y0f,     0), 63);
    int iy1 = min(max((int)y0f + 1, 0), 63);

    int bimg = tb >> 5;
    const float* img = fmap + (size_t)bimg * 64 * 64 * 128;
    float Ia = img[(iy0 * 64 + ix0) * 128 + ch];
    float Ib = img[(iy0 * 64 + ix1) * 128 + ch];
    float Ic = img[(iy1 * 64 + ix0) * 128 + ch];
    float Id = img[(iy1 * 64 + ix1) * 128 + ch];

    float x0v = (float)ix0, x1v = (float)ix1;
    float y0v = (float)iy0, y1v = (float)iy1;
    float wa = (x1v - x) * (y1v - y);
    float wb = (x1v - x) * (y - y0v);
    float wc = (x - x0v) * (y1v - y);
    float wd = (x - x0v) * (y - y0v);

    float val = (Ia * wa + Ib * wb + Ic * wc + Id * wd) * mask;

    float* outp = (dir == 0) ? out_h : out_v;
    outp[el] = val;

    if (within == 0) {
        ((dir == 0) ? out_w : out_hh)[tb] = (float)n;
    }
}

// ---------------------------------------------------------------------------
extern "C" void kernel_launch(void* const* d_in, const int* in_sizes, int n_in,
                              void* d_out, int out_size, void* d_ws, size_t ws_size,
                              hipStream_t stream) {
    const float* fmap = (const float*)d_in[0];   // (4,64,64,128)
    const float* bbox = (const float*)d_in[1];   // (4,64,64,5)
    float* out = (float*)d_out;

    // output layout (flat, return order):
    //   nms_boxes (4,32,4)        =       512
    //   h_roi     (4,32,8,64,128) = 8,388,608
    //   widths    (4,32)          =       128
    //   v_roi     (4,32,64,8,128) = 8,388,608
    //   heights   (4,32)          =       128
    // total = 16,777,984
    float* out_nms = out;
    float* out_h   = out + 512;
    float* out_w   = out_h + ROI_N;
    float* out_v   = out_w + 128;
    float* out_hh  = out_v + ROI_N;

    nms_kernel<<<NB, 256, 0, stream>>>(bbox, out_nms);
    roi_kernel<<<(2 * ROI_N) / 256, 256, 0, stream>>>(fmap, out_nms,
                                                      out_h, out_w, out_v, out_hh);
}

// Round 5
// 145.042 us; speedup vs baseline: 1.6498x; 1.6498x over previous
//
#include <hip/hip_runtime.h>
#include <hip/hip_bf16.h>
#include <math.h>

#define NPIX 4096      // 64*64
#define MAXB 32
#define NB   4
#define ROI_N 8388608          // 4*32*8*64*128 elements per roi tensor
#define QTOT (ROI_N / 4)       // float4 quarter-elements per roi tensor

// ---------------------------------------------------------------------------
// Kernel 1: per-batch score/box reconstruct + serial NMS (one block per batch)
// + epilogue computing per-(dir,box) ROI params into d_ws and widths/heights.
// Candidate data lives in REGISTERS (static-indexed via full unroll);
// argmax + suppression are branchless. LDS only for winner lookup / reduce.
// ---------------------------------------------------------------------------
__global__ __launch_bounds__(256) void nms_kernel(const float* __restrict__ bbox,
                                                  float* __restrict__ out_nms,
                                                  float* __restrict__ params,
                                                  float* __restrict__ out_w,
                                                  float* __restrict__ out_hh)
{
    const int b = blockIdx.x;
    const int t = threadIdx.x;

    __shared__ float s_box[NPIX][4];   // 64 KB, winner lookup only
    __shared__ float s_sel[MAXB][4];   // selected (keep-applied) boxes
    __shared__ float s_rv[4];
    __shared__ int   s_ri[4];

    float rs[16], rx1[16], ry1[16], rx2[16], ry2[16], rar[16];

    const float* src = bbox + (size_t)b * NPIX * 5;

    #pragma unroll
    for (int i = 0; i < 16; ++i) {
        int p = i * 256 + t;
        int y = p >> 6, x = p & 63;
        float c0 = src[p * 5 + 0];
        float c1 = src[p * 5 + 1];
        float c2 = src[p * 5 + 2];
        float c3 = src[p * 5 + 3];
        float c4 = src[p * 5 + 4];
        float sc = 1.0f / (1.0f + expf(-c0));
        float x1 = 8.0f * ((float)x - c1);
        float y1 = 8.0f * ((float)y - c2);
        float x2 = 8.0f * ((float)x + c3);
        float y2 = 8.0f * ((float)y + c4);
        rs[i] = sc;
        rx1[i] = x1; ry1[i] = y1; rx2[i] = x2; ry2[i] = y2;
        rar[i] = (x2 - x1) * (y2 - y1);
        s_box[p][0] = x1; s_box[p][1] = y1; s_box[p][2] = x2; s_box[p][3] = y2;
    }
    __syncthreads();

    unsigned valid = 0xFFFFu;   // bit i <-> candidate p = i*256 + t

    for (int it = 0; it < MAXB; ++it) {
        // ---- branchless local argmax (lowest-p tie-break preserved) ----
        float best = -INFINITY;
        int   bidx = 0x7FFFFFFF;
        #pragma unroll
        for (int i = 0; i < 16; ++i) {
            float vv  = ((valid >> i) & 1u) ? rs[i] : -INFINITY;
            bool take = vv > best;               // strict > keeps lowest p
            bidx = take ? (i * 256 + t) : bidx;
            best = take ? vv : best;
        }
        // ---- wave butterfly reduce ----
        #pragma unroll
        for (int off = 32; off; off >>= 1) {
            float ov = __shfl_xor(best, off);
            int   oi = __shfl_xor(bidx, off);
            bool take = (ov > best) || (ov == best && oi < bidx);
            best = take ? ov : best;
            bidx = take ? oi : bidx;
        }
        if ((t & 63) == 0) { s_rv[t >> 6] = best; s_ri[t >> 6] = bidx; }
        __syncthreads();
        best = s_rv[0]; bidx = s_ri[0];
        #pragma unroll
        for (int wv = 1; wv < 4; ++wv) {
            float ov = s_rv[wv]; int oi = s_ri[wv];
            bool take = (ov > best) || (ov == best && oi < bidx);
            best = take ? ov : best;
            bidx = take ? oi : bidx;
        }

        bool ok = (best > -INFINITY);
        int  jj = ok ? bidx : 0;                 // clamp to avoid OOB LDS read
        float bx1 = s_box[jj][0], by1 = s_box[jj][1];
        float bx2 = s_box[jj][2], by2 = s_box[jj][3];
        float barea = (bx2 - bx1) * (by2 - by1);

        if (t == 0) {
            bool keep = ok && (best >= 0.3f);
            float o0 = keep ? bx1 : 0.f, o1 = keep ? by1 : 0.f;
            float o2 = keep ? bx2 : 0.f, o3 = keep ? by2 : 0.f;
            float* o = out_nms + ((size_t)b * MAXB + it) * 4;
            o[0] = o0; o[1] = o1; o[2] = o2; o[3] = o3;
            s_sel[it][0] = o0; s_sel[it][1] = o1;
            s_sel[it][2] = o2; s_sel[it][3] = o3;
        }

        // ---- branchless suppression vs winner (registers only) ----
        if (ok) {
            #pragma unroll
            for (int i = 0; i < 16; ++i) {
                float iw = fmaxf(fminf(rx2[i], bx2) - fmaxf(rx1[i], bx1), 0.f);
                float ih = fmaxf(fminf(ry2[i], by2) - fmaxf(ry1[i], by1), 0.f);
                float inter = iw * ih;
                float iou = inter / (rar[i] + barea - inter + 1e-9f);
                valid &= ~(((iou > 0.5f) ? 1u : 0u) << i);
            }
        }
        __syncthreads();   // protects s_rv/s_ri and (last iter) s_sel
    }

    // ---- epilogue: per-(dir, box) ROI params, once per box ----
    if (t < 64) {
        int dir = t >> 5, bx = t & 31;
        float x1 = s_sel[bx][0] * 0.125f, y1 = s_sel[bx][1] * 0.125f;  // exact /8
        float x2 = s_sel[bx][2] * 0.125f, y2 = s_sel[bx][3] * 0.125f;
        float w = x2 - x1, h = y2 - y1;
        bool is_dir = (dir == 0) ? (w >= h) : (w < h);
        if (!is_dir) { x1 = 0.f; y1 = 0.f; x2 = 0.f; y2 = 0.f; }
        w = x2 - x1; h = y2 - y1;
        bool  non_zero = (w >= 0.1f) || (h >= 0.1f);
        float bw = (w <= 0.f) ? 1e-4f : w;
        float bh = (h <= 0.f) ? 1e-4f : h;
        float ratio = non_zero ? ((dir == 0) ? __fdiv_rn(bw, bh) : __fdiv_rn(bh, bw)) : 0.f;
        int   n = (int)fminf(ceilf(ratio * 8.0f), 64.0f);   // *8 exact
        float length_f = fmaxf((float)n, 2.0f);
        float fmask = non_zero ? 1.f : 0.f;
        float map_w, map_h;
        if (dir == 0) { map_w = __fdiv_rn(bw, length_f - 1.0f); map_h = __fdiv_rn(bh, 7.0f); }
        else          { map_w = __fdiv_rn(bw, 7.0f);            map_h = __fdiv_rn(bh, length_f - 1.0f); }
        int gtb = b * MAXB + bx;
        float* P = params + ((size_t)dir * 128 + gtb) * 8;
        P[0] = x1; P[1] = y1; P[2] = map_w; P[3] = map_h;
        P[4] = (float)n; P[5] = fmask;
        ((dir == 0) ? out_w : out_hh)[gtb] = (float)n;
    }
}

// ---------------------------------------------------------------------------
// Kernel 2: ROI pooling, 4 channels per thread (float4), params precomputed.
// FP contraction OFF: value math must round exactly like the numpy ref.
// ---------------------------------------------------------------------------
#pragma clang fp contract(off)

__global__ __launch_bounds__(256) void roi_kernel(const float* __restrict__ fmap,
                                                  const float* __restrict__ params,
                                                  float* __restrict__ out_h,
                                                  float* __restrict__ out_v)
{
    int idx = blockIdx.x * 256 + threadIdx.x;    // [0, 2*QTOT)
    int dir = (idx >= QTOT) ? 1 : 0;
    int e   = idx - dir * QTOT;                  // [0, QTOT)
    int tb  = e >> 14;                           // 512 pos * 32 ch4 per box
    int within = e & 16383;
    int pos = within >> 5;                       // [0,512)
    int ch4 = within & 31;                       // channel group (4 ch)

    const float* P = params + ((size_t)dir * 128 + tb) * 8;
    float bz0x = P[0], bz0y = P[1], map_w = P[2], map_h = P[3];
    int   n     = (int)P[4];
    float fmask = P[5];

    int rr, cc; float mask;
    if (dir == 0) { rr = pos >> 6; cc = pos & 63; mask = (cc < n) ? fmask : 0.f; }
    else          { rr = pos >> 3; cc = pos & 7;  mask = (rr < n) ? fmask : 0.f; }

    int el = (tb << 16) | (pos << 7) | (ch4 << 2);
    float* outp = ((dir == 0) ? out_h : out_v) + el;

    if (mask == 0.f) {                           // masked: pooled*0 == ±0; store +0
        *(float4*)outp = make_float4(0.f, 0.f, 0.f, 0.f);
        return;
    }

    // separately-rounded mul then add (no FMA) — floor() is discontinuous
    float x = __fadd_rn(__fmul_rn((float)cc, map_w), bz0x);
    float y = __fadd_rn(__fmul_rn((float)rr, map_h), bz0y);

    float x0f = floorf(x), y0f = floorf(y);
    int ix0 = min(max((int)x0f,     0), 63);
    int ix1 = min(max((int)x0f + 1, 0), 63);
    int iy0 = min(max((int)y0f,     0), 63);
    int iy1 = min(max((int)y0f + 1, 0), 63);

    const float* img = fmap + ((size_t)(tb >> 5)) * (64 * 64 * 128) + (ch4 << 2);
    float4 Ia = *(const float4*)(img + (iy0 * 64 + ix0) * 128);
    float4 Ib = *(const float4*)(img + (iy0 * 64 + ix1) * 128);
    float4 Ic = *(const float4*)(img + (iy1 * 64 + ix0) * 128);
    float4 Id = *(const float4*)(img + (iy1 * 64 + ix1) * 128);

    float x0v = (float)ix0, x1v = (float)ix1;
    float y0v = (float)iy0, y1v = (float)iy1;
    float wa = (x1v - x) * (y1v - y);
    float wb = (x1v - x) * (y - y0v);
    float wc = (x - x0v) * (y1v - y);
    float wd = (x - x0v) * (y - y0v);

    float4 o;
    o.x = (Ia.x * wa + Ib.x * wb + Ic.x * wc + Id.x * wd) * mask;
    o.y = (Ia.y * wa + Ib.y * wb + Ic.y * wc + Id.y * wd) * mask;
    o.z = (Ia.z * wa + Ib.z * wb + Ic.z * wc + Id.z * wd) * mask;
    o.w = (Ia.w * wa + Ib.w * wb + Ic.w * wc + Id.w * wd) * mask;
    *(float4*)outp = o;
}

// ---------------------------------------------------------------------------
extern "C" void kernel_launch(void* const* d_in, const int* in_sizes, int n_in,
                              void* d_out, int out_size, void* d_ws, size_t ws_size,
                              hipStream_t stream) {
    const float* fmap = (const float*)d_in[0];   // (4,64,64,128)
    const float* bbox = (const float*)d_in[1];   // (4,64,64,5)
    float* out = (float*)d_out;

    // output layout (flat, return order):
    //   nms_boxes (4,32,4)        =       512
    //   h_roi     (4,32,8,64,128) = 8,388,608
    //   widths    (4,32)          =       128
    //   v_roi     (4,32,64,8,128) = 8,388,608
    //   heights   (4,32)          =       128
    float* out_nms = out;
    float* out_h   = out + 512;
    float* out_w   = out_h + ROI_N;
    float* out_v   = out_w + 128;
    float* out_hh  = out_v + ROI_N;

    float* params = (float*)d_ws;   // [2][128][8] floats = 8 KB

    nms_kernel<<<NB, 256, 0, stream>>>(bbox, out_nms, params, out_w, out_hh);
    roi_kernel<<<(2 * QTOT) / 256, 256, 0, stream>>>(fmap, params, out_h, out_v);
}

// Round 6
// 139.565 us; speedup vs baseline: 1.7146x; 1.0392x over previous
//
#include <hip/hip_runtime.h>
#include <hip/hip_bf16.h>
#include <math.h>

// Exact numpy rounding everywhere: no FMA contraction in this file.
#pragma clang fp contract(off)

#define NPIX 4096      // 64*64
#define MAXB 32
#define NB   4
#define ROI_N 8388608          // 4*32*8*64*128 elements per roi tensor
#define OTOT (ROI_N / 8)       // 8-channel work items per roi tensor

// ---------------------------------------------------------------------------
// Kernel 1: per-batch score/box reconstruct + serial NMS (one block per batch)
// + epilogue computing per-(dir,box) ROI params into d_ws and widths/heights.
// Per iteration: ONE fused register pass (suppress-vs-prev-winner + argmax),
// 6-step butterfly, ONE barrier (double-buffered reduce slots), broadcast
// winner-box read. Candidates live in registers (static-indexed full unroll).
// ---------------------------------------------------------------------------
__global__ __launch_bounds__(256) void nms_kernel(const float* __restrict__ bbox,
                                                  float* __restrict__ out_nms,
                                                  float* __restrict__ params,
                                                  float* __restrict__ out_w,
                                                  float* __restrict__ out_hh)
{
    const int b = blockIdx.x;
    const int t = threadIdx.x;

    __shared__ float s_box[NPIX][4];     // 64 KB, winner broadcast lookup
    __shared__ float s_sel[MAXB][4];     // selected (keep-applied) boxes
    __shared__ float s_red[2][4][2];     // [buf][wave][score, idx-as-float]

    float rs[16], rx1[16], ry1[16], rx2[16], ry2[16], rar[16];

    const float* src = bbox + (size_t)b * NPIX * 5;

    #pragma unroll
    for (int i = 0; i < 16; ++i) {
        int p = i * 256 + t;
        int y = p >> 6, x = p & 63;
        float c0 = src[p * 5 + 0];
        float c1 = src[p * 5 + 1];
        float c2 = src[p * 5 + 2];
        float c3 = src[p * 5 + 3];
        float c4 = src[p * 5 + 4];
        float sc = 1.0f / (1.0f + expf(-c0));   // keep formulation byte-identical
        float x1 = 8.0f * ((float)x - c1);
        float y1 = 8.0f * ((float)y - c2);
        float x2 = 8.0f * ((float)x + c3);
        float y2 = 8.0f * ((float)y + c4);
        rs[i] = sc;
        rx1[i] = x1; ry1[i] = y1; rx2[i] = x2; ry2[i] = y2;
        rar[i] = (x2 - x1) * (y2 - y1);
        s_box[p][0] = x1; s_box[p][1] = y1; s_box[p][2] = x2; s_box[p][3] = y2;
    }
    __syncthreads();

    unsigned valid = 0xFFFFu;            // bit i <-> candidate p = i*256 + t
    // dummy previous winner: IoU vs it is exactly 0 for any real box
    float wx1 = -1e30f, wy1 = -1e30f, wx2 = -1e30f, wy2 = -1e30f, warea = 0.f;

    for (int it = 0; it < MAXB; ++it) {
        // ---- fused: suppress vs previous winner + branchless argmax ----
        float best = -INFINITY;
        int   bidx = 0x7FFFFFFF;
        #pragma unroll
        for (int i = 0; i < 16; ++i) {
            float iw = fmaxf(fminf(rx2[i], wx2) - fmaxf(rx1[i], wx1), 0.f);
            float ih = fmaxf(fminf(ry2[i], wy2) - fmaxf(ry1[i], wy1), 0.f);
            float inter = iw * ih;
            float iou = __fdiv_rn(inter, rar[i] + warea - inter + 1e-9f);
            valid &= ~(((iou > 0.5f) ? 1u : 0u) << i);
            float vv = ((valid >> i) & 1u) ? rs[i] : -INFINITY;
            bool take = vv > best;       // strict > keeps lowest p (i ascending)
            bidx = take ? (i * 256 + t) : bidx;
            best = take ? vv : best;
        }
        // ---- wave butterfly reduce ----
        #pragma unroll
        for (int off = 32; off; off >>= 1) {
            float ov = __shfl_xor(best, off);
            int   oi = __shfl_xor(bidx, off);
            bool take = (ov > best) || (ov == best && oi < bidx);
            best = take ? ov : best;
            bidx = take ? oi : bidx;
        }
        int buf = it & 1;
        if ((t & 63) == 0) {
            s_red[buf][t >> 6][0] = best;
            s_red[buf][t >> 6][1] = __int_as_float(bidx);
        }
        __syncthreads();                 // the ONLY barrier in the iteration
        best = s_red[buf][0][0]; bidx = __float_as_int(s_red[buf][0][1]);
        #pragma unroll
        for (int wv = 1; wv < 4; ++wv) {
            float ov = s_red[buf][wv][0];
            int   oi = __float_as_int(s_red[buf][wv][1]);
            bool take = (ov > best) || (ov == best && oi < bidx);
            best = take ? ov : best;
            bidx = take ? oi : bidx;
        }

        // winner box broadcast (clamped; if best==-inf no valid bits exist,
        // so a garbage winner suppresses nothing and output is zeroed anyway)
        int jj = min(bidx, NPIX - 1);
        wx1 = s_box[jj][0]; wy1 = s_box[jj][1];
        wx2 = s_box[jj][2]; wy2 = s_box[jj][3];
        warea = (wx2 - wx1) * (wy2 - wy1);   // same formula as rar -> bit-exact

        if (t == 0) {
            bool keep = (best >= 0.3f);      // -inf fails this too
            float o0 = keep ? wx1 : 0.f, o1 = keep ? wy1 : 0.f;
            float o2 = keep ? wx2 : 0.f, o3 = keep ? wy2 : 0.f;
            float* o = out_nms + ((size_t)b * MAXB + it) * 4;
            o[0] = o0; o[1] = o1; o[2] = o2; o[3] = o3;
            s_sel[it][0] = o0; s_sel[it][1] = o1;
            s_sel[it][2] = o2; s_sel[it][3] = o3;
        }
    }
    __syncthreads();                      // publish s_sel to epilogue

    // ---- epilogue: per-(dir, box) ROI params, once per box ----
    if (t < 64) {
        int dir = t >> 5, bx = t & 31;
        float x1 = s_sel[bx][0] * 0.125f, y1 = s_sel[bx][1] * 0.125f;  // exact /8
        float x2 = s_sel[bx][2] * 0.125f, y2 = s_sel[bx][3] * 0.125f;
        float w = x2 - x1, h = y2 - y1;
        bool is_dir = (dir == 0) ? (w >= h) : (w < h);
        if (!is_dir) { x1 = 0.f; y1 = 0.f; x2 = 0.f; y2 = 0.f; }
        w = x2 - x1; h = y2 - y1;
        bool  non_zero = (w >= 0.1f) || (h >= 0.1f);
        float bw = (w <= 0.f) ? 1e-4f : w;
        float bh = (h <= 0.f) ? 1e-4f : h;
        float ratio = non_zero ? ((dir == 0) ? __fdiv_rn(bw, bh) : __fdiv_rn(bh, bw)) : 0.f;
        int   n = (int)fminf(ceilf(ratio * 8.0f), 64.0f);   // *8 exact
        float length_f = fmaxf((float)n, 2.0f);
        float fmask = non_zero ? 1.f : 0.f;
        float map_w, map_h;
        if (dir == 0) { map_w = __fdiv_rn(bw, length_f - 1.0f); map_h = __fdiv_rn(bh, 7.0f); }
        else          { map_w = __fdiv_rn(bw, 7.0f);            map_h = __fdiv_rn(bh, length_f - 1.0f); }
        int gtb = b * MAXB + bx;
        float* P = params + ((size_t)dir * 128 + gtb) * 8;
        P[0] = x1; P[1] = y1; P[2] = map_w; P[3] = map_h;
        P[4] = (float)n; P[5] = fmask; P[6] = 0.f; P[7] = 0.f;
        ((dir == 0) ? out_w : out_hh)[gtb] = (float)n;
    }
}

// ---------------------------------------------------------------------------
// Kernel 2: ROI pooling, 8 channels per thread (2x float4), params precomputed.
// ---------------------------------------------------------------------------
__global__ __launch_bounds__(256) void roi_kernel(const float* __restrict__ fmap,
                                                  const float* __restrict__ params,
                                                  float* __restrict__ out_h,
                                                  float* __restrict__ out_v)
{
    int idx = blockIdx.x * 256 + threadIdx.x;    // [0, 2*OTOT)
    int dir = (idx >= OTOT) ? 1 : 0;
    int e   = idx - dir * OTOT;                  // [0, OTOT)
    int tb  = e >> 13;                           // 512 pos * 16 ch8 per box
    int within = e & 8191;
    int pos = within >> 4;                       // [0,512)
    int ch8 = within & 15;                       // channel group (8 ch)

    const float4* P4 = (const float4*)(params + ((size_t)dir * 128 + tb) * 8);
    float4 p0 = P4[0];
    float4 p1 = P4[1];
    float bz0x = p0.x, bz0y = p0.y, map_w = p0.z, map_h = p0.w;
    int   n     = (int)p1.x;
    float fmask = p1.y;

    int rr, cc; float mask;
    if (dir == 0) { rr = pos >> 6; cc = pos & 63; mask = (cc < n) ? fmask : 0.f; }
    else          { rr = pos >> 3; cc = pos & 7;  mask = (rr < n) ? fmask : 0.f; }

    int el = (tb << 16) | (pos << 7) | (ch8 << 3);
    float* outp = ((dir == 0) ? out_h : out_v) + el;

    if (mask == 0.f) {                           // masked: pooled*0 == +0
        float4 z = make_float4(0.f, 0.f, 0.f, 0.f);
        *(float4*)outp = z;
        *(float4*)(outp + 4) = z;
        return;
    }

    // separately-rounded mul then add (no FMA) — floor() is discontinuous
    float x = __fadd_rn(__fmul_rn((float)cc, map_w), bz0x);
    float y = __fadd_rn(__fmul_rn((float)rr, map_h), bz0y);

    float x0f = floorf(x), y0f = floorf(y);
    int ix0 = min(max((int)x0f,     0), 63);
    int ix1 = min(max((int)x0f + 1, 0), 63);
    int iy0 = min(max((int)y0f,     0), 63);
    int iy1 = min(max((int)y0f + 1, 0), 63);

    const float* img = fmap + ((size_t)(tb >> 5)) * (64 * 64 * 128) + (ch8 << 3);
    const float* pa = img + (iy0 * 64 + ix0) * 128;
    const float* pb = img + (iy0 * 64 + ix1) * 128;
    const float* pc = img + (iy1 * 64 + ix0) * 128;
    const float* pd = img + (iy1 * 64 + ix1) * 128;
    float4 Ia0 = *(const float4*)pa,       Ia1 = *(const float4*)(pa + 4);
    float4 Ib0 = *(const float4*)pb,       Ib1 = *(const float4*)(pb + 4);
    float4 Ic0 = *(const float4*)pc,       Ic1 = *(const float4*)(pc + 4);
    float4 Id0 = *(const float4*)pd,       Id1 = *(const float4*)(pd + 4);

    float x0v = (float)ix0, x1v = (float)ix1;
    float y0v = (float)iy0, y1v = (float)iy1;
    float wa = (x1v - x) * (y1v - y);
    float wb = (x1v - x) * (y - y0v);
    float wc = (x - x0v) * (y1v - y);
    float wd = (x - x0v) * (y - y0v);

    float4 o0, o1;
    o0.x = (Ia0.x * wa + Ib0.x * wb + Ic0.x * wc + Id0.x * wd) * mask;
    o0.y = (Ia0.y * wa + Ib0.y * wb + Ic0.y * wc + Id0.y * wd) * mask;
    o0.z = (Ia0.z * wa + Ib0.z * wb + Ic0.z * wc + Id0.z * wd) * mask;
    o0.w = (Ia0.w * wa + Ib0.w * wb + Ic0.w * wc + Id0.w * wd) * mask;
    o1.x = (Ia1.x * wa + Ib1.x * wb + Ic1.x * wc + Id1.x * wd) * mask;
    o1.y = (Ia1.y * wa + Ib1.y * wb + Ic1.y * wc + Id1.y * wd) * mask;
    o1.z = (Ia1.z * wa + Ib1.z * wb + Ic1.z * wc + Id1.z * wd) * mask;
    o1.w = (Ia1.w * wa + Ib1.w * wb + Ic1.w * wc + Id1.w * wd) * mask;
    *(float4*)outp = o0;
    *(float4*)(outp + 4) = o1;
}

// ---------------------------------------------------------------------------
extern "C" void kernel_launch(void* const* d_in, const int* in_sizes, int n_in,
                              void* d_out, int out_size, void* d_ws, size_t ws_size,
                              hipStream_t stream) {
    const float* fmap = (const float*)d_in[0];   // (4,64,64,128)
    const float* bbox = (const float*)d_in[1];   // (4,64,64,5)
    float* out = (float*)d_out;

    // output layout (flat, return order):
    //   nms_boxes (4,32,4)        =       512
    //   h_roi     (4,32,8,64,128) = 8,388,608
    //   widths    (4,32)          =       128
    //   v_roi     (4,32,64,8,128) = 8,388,608
    //   heights   (4,32)          =       128
    float* out_nms = out;
    float* out_h   = out + 512;
    float* out_w   = out_h + ROI_N;
    float* out_v   = out_w + 128;
    float* out_hh  = out_v + ROI_N;

    float* params = (float*)d_ws;   // [2][128][8] floats = 8 KB

    nms_kernel<<<NB, 256, 0, stream>>>(bbox, out_nms, params, out_w, out_hh);
    roi_kernel<<<(2 * OTOT) / 256, 256, 0, stream>>>(fmap, params, out_h, out_v);
}